// Round 5
// baseline (329.985 us; speedup 1.0000x reference)
//
#include <hip/hip_runtime.h>
#include <hip/hip_bf16.h>

// Single-head causal attention with value-residual mix.
// B=16, T=2048, C=768, H=64. Inputs/outputs f32; internal compute bf16 MFMA.
// Outputs (concat flat, f32): y=[B,T,64], then v1=[B,T,64].
//
// ws layout: q bf16 [B*T,64] (4.19MB) | WT bf16 [3][64][768] (288KB) |
//            WprojT bf16 [64][64] (8KB).  Total 4.50MB.
// out layout during compute: out0 = y (f32), out1 region = k bf16 + vT bf16
//            scratch (exactly 8.39MB), overwritten by f32 v1 copy at the end.

constexpr int BATCH = 16;
constexpr int TSEQ  = 2048;
constexpr int CEMB  = 768;
constexpr int HS    = 64;
constexpr size_t NTOK    = (size_t)BATCH * TSEQ;  // 32768
constexpr size_t OUTHALF = NTOK * HS;             // 2,097,152 elements

typedef __bf16 bf16x4 __attribute__((ext_vector_type(4)));
typedef __bf16 bf16x8 __attribute__((ext_vector_type(8)));
typedef float  f32x4  __attribute__((ext_vector_type(4)));

// ---------------------------------------------------------------------------
// Kernel 0: transpose weights to bf16.
// blocks 0..35: WT[m][h][c] = Wm[c][h]  (m = bid/12, c-tile = bid%12)
// block 36:     WprojT[h'][h] = Wproj[h][h']
// ---------------------------------------------------------------------------
__global__ __launch_bounds__(256) void prep_kernel(
    const float* __restrict__ wk, const float* __restrict__ wq,
    const float* __restrict__ wv, const float* __restrict__ wproj,
    __bf16* __restrict__ wt, __bf16* __restrict__ wpt)
{
    __shared__ __bf16 t[64][66];
    const int bid = blockIdx.x;
    if (bid < 36) {
        const int m = bid / 12, c0 = (bid % 12) * 64;
        const float* src = (m == 0) ? wk : (m == 1) ? wq : wv;
        for (int i = threadIdx.x; i < 4096; i += 256) {
            const int c = i >> 6, h = i & 63;
            t[c][h] = (__bf16)src[(size_t)(c0 + c) * HS + h];
        }
        __syncthreads();
        for (int i = threadIdx.x; i < 4096; i += 256) {
            const int h = i >> 6, c = i & 63;
            wt[(size_t)m * HS * CEMB + (size_t)h * CEMB + c0 + c] = t[c][h];
        }
    } else {
        for (int i = threadIdx.x; i < 4096; i += 256) {
            const int h = i >> 6, hp = i & 63;
            t[h][hp] = (__bf16)wproj[i];          // t[h][h'] = Wproj[h][h']
        }
        __syncthreads();
        for (int i = threadIdx.x; i < 4096; i += 256) {
            const int hp = i >> 6, h = i & 63;
            wpt[i] = t[h][hp];                     // wpt[h'][h]
        }
    }
}

// ---------------------------------------------------------------------------
// Kernel 1: QKV projection, no LDS, no barriers.
// k=x@Wk (row-major), q=x@Wq (row-major), vT[b][h][t] = ((1-lam)x@Wv+lam*v1)^T
// Grid: (B*T)/64 blocks x 256 threads (4 waves x 16 rows).
// ---------------------------------------------------------------------------
__global__ __launch_bounds__(256) void qkv_kernel(
    const float* __restrict__ x,      // [B*T, 768]
    const float* __restrict__ v1,     // [B*T, 64]
    const __bf16* __restrict__ wt,    // [3][64][768]
    const float* __restrict__ lamb_p,
    __bf16* __restrict__ kk,          // [B*T, 64]
    __bf16* __restrict__ qq,          // [B*T, 64]
    __bf16* __restrict__ vt)          // [B][64][2048]
{
    const int wave = threadIdx.x >> 6;
    const int lane = threadIdx.x & 63;
    const int l16  = lane & 15;
    const int quad = lane >> 4;
    const size_t row0 = (size_t)blockIdx.x * 64;

    f32x4 acc[3][4];
    #pragma unroll
    for (int m = 0; m < 3; ++m)
        #pragma unroll
        for (int nt = 0; nt < 4; ++nt)
            acc[m][nt] = (f32x4){0.f, 0.f, 0.f, 0.f};

    const size_t arow = row0 + wave * 16 + l16;
    for (int c0 = 0; c0 < CEMB; c0 += 64) {
        const float* xb = x + arow * CEMB + c0 + quad * 8;
        f32x4 a0 = *(const f32x4*)(xb);
        f32x4 a1 = *(const f32x4*)(xb + 4);
        f32x4 b0 = *(const f32x4*)(xb + 32);
        f32x4 b1 = *(const f32x4*)(xb + 36);
        bf16x8 xa0, xa1;
        #pragma unroll
        for (int i = 0; i < 4; ++i) {
            xa0[i]     = (__bf16)a0[i];
            xa0[i + 4] = (__bf16)a1[i];
            xa1[i]     = (__bf16)b0[i];
            xa1[i + 4] = (__bf16)b1[i];
        }
        #pragma unroll
        for (int m = 0; m < 3; ++m) {
            const __bf16* wm = wt + (size_t)m * HS * CEMB;
            #pragma unroll
            for (int nt = 0; nt < 4; ++nt) {
                const __bf16* wr = wm + (size_t)(nt * 16 + l16) * CEMB + c0 + quad * 8;
                bf16x8 wf0 = *(const bf16x8*)(wr);
                bf16x8 wf1 = *(const bf16x8*)(wr + 32);
                acc[m][nt] = __builtin_amdgcn_mfma_f32_16x16x32_bf16(xa0, wf0, acc[m][nt], 0, 0, 0);
                acc[m][nt] = __builtin_amdgcn_mfma_f32_16x16x32_bf16(xa1, wf1, acc[m][nt], 0, 0, 0);
            }
        }
    }

    const float lam = lamb_p[0];
    // C/D layout: row = quad*4+r, col = nt*16+l16
    const size_t rbase = row0 + wave * 16 + quad * 4;
    const int b  = (int)(rbase >> 11);
    const int t0 = (int)(rbase & 2047);
    __bf16* vtb = vt + (size_t)b * HS * TSEQ;
    #pragma unroll
    for (int nt = 0; nt < 4; ++nt) {
        const int col = nt * 16 + l16;
        bf16x4 pk;
        #pragma unroll
        for (int r = 0; r < 4; ++r) {
            const size_t idx = (rbase + r) * HS + col;
            kk[idx] = (__bf16)acc[0][nt][r];
            qq[idx] = (__bf16)acc[1][nt][r];
            pk[r] = (__bf16)((1.0f - lam) * acc[2][nt][r] + lam * v1[idx]);
        }
        *(bf16x4*)(vtb + (size_t)col * TSEQ + t0) = pk;
    }
}

// ---------------------------------------------------------------------------
// Kernel 2: flash attention + fused projection.
// Grid: B*(T/16) = 2048 blocks of 256. Block owns 16 q-rows; the 4 waves
// split the causal s-tile range (wave w: tiles w, w+4, ...). No barriers in
// the main loop (K/V^T direct from global, P transpose in per-wave LDS).
// Two-barrier merge of (m,l,O) + wave-0 projection epilogue.
// ---------------------------------------------------------------------------
__global__ __launch_bounds__(256) void attn_kernel(
    const __bf16* __restrict__ q,     // [B*T, 64]
    const __bf16* __restrict__ k,     // [B*T, 64]
    const __bf16* __restrict__ vt,    // [B][64][2048]
    const __bf16* __restrict__ wpt,   // [64][64] = Wproj^T
    const float* __restrict__ bproj,  // [64]
    float* __restrict__ y)            // [B*T, 64] f32
{
    __shared__ __bf16 plds[4][16][72];    // per-wave P (loop) / O (merge)
    __shared__ float  mlm[4][16], mll[4][16];

    const int b    = blockIdx.x >> 7;
    const int j    = blockIdx.x & 127;       // q-row block: rows [16j, 16j+16)
    const int wave = threadIdx.x >> 6;
    const int lane = threadIdx.x & 63;
    const int l16  = lane & 15;
    const int quad = lane >> 4;

    const size_t tokbase = (size_t)b * TSEQ + j * 16;
    const __bf16* qbase = q + (tokbase + l16) * HS + quad * 8;
    bf16x8 qf0 = *(const bf16x8*)(qbase);
    bf16x8 qf1 = *(const bf16x8*)(qbase + 32);
    const __bf16* kb  = k  + (size_t)b * TSEQ * HS;
    const __bf16* vtb = vt + (size_t)b * HS * TSEQ;

    f32x4 o_acc[4];
    #pragma unroll
    for (int nt = 0; nt < 4; ++nt) o_acc[nt] = (f32x4){0.f, 0.f, 0.f, 0.f};
    float m_i[4], l_i[4];
    #pragma unroll
    for (int r = 0; r < 4; ++r) { m_i[r] = -1e30f; l_i[r] = 0.f; }

    const float sc2 = 0.125f * 1.44269504f;  // 1/sqrt(64) * log2(e)
    const int tdiag = j >> 2;

    for (int t = wave; t <= tdiag; t += 4) {
        const int s0 = t * 64;
        // S = Q K^T  (K B-frags direct from global, b128)
        f32x4 sc[4];
        #pragma unroll
        for (int nt = 0; nt < 4; ++nt) {
            const __bf16* kbp = kb + (size_t)(s0 + nt * 16 + l16) * HS + quad * 8;
            bf16x8 kf0 = *(const bf16x8*)(kbp);
            bf16x8 kf1 = *(const bf16x8*)(kbp + 32);
            f32x4 c = (f32x4){0.f, 0.f, 0.f, 0.f};
            c = __builtin_amdgcn_mfma_f32_16x16x32_bf16(qf0, kf0, c, 0, 0, 0);
            c = __builtin_amdgcn_mfma_f32_16x16x32_bf16(qf1, kf1, c, 0, 0, 0);
            sc[nt] = c;
        }

        float vals[4][4];
        if (t == tdiag) {   // diagonal tile: mask s > trow (log2 domain)
            #pragma unroll
            for (int nt = 0; nt < 4; ++nt)
                #pragma unroll
                for (int r = 0; r < 4; ++r) {
                    const int s = s0 + nt * 16 + l16;
                    const int trow = j * 16 + quad * 4 + r;
                    vals[nt][r] = (s <= trow) ? sc[nt][r] * sc2 : -1e30f;
                }
        } else {
            #pragma unroll
            for (int nt = 0; nt < 4; ++nt)
                #pragma unroll
                for (int r = 0; r < 4; ++r) vals[nt][r] = sc[nt][r] * sc2;
        }

        // Online softmax in exp2 domain (row r spread across the quad's 16 lanes)
        float mx[4];
        #pragma unroll
        for (int r = 0; r < 4; ++r) {
            mx[r] = fmaxf(fmaxf(vals[0][r], vals[1][r]), fmaxf(vals[2][r], vals[3][r]));
            #pragma unroll
            for (int off = 1; off < 16; off <<= 1)
                mx[r] = fmaxf(mx[r], __shfl_xor(mx[r], off));
        }
        float alpha[4];
        #pragma unroll
        for (int r = 0; r < 4; ++r) {
            const float mn = fmaxf(m_i[r], mx[r]);
            alpha[r] = exp2f(m_i[r] - mn);
            m_i[r] = mn;
        }
        float rs[4] = {0.f, 0.f, 0.f, 0.f};
        #pragma unroll
        for (int nt = 0; nt < 4; ++nt)
            #pragma unroll
            for (int r = 0; r < 4; ++r) {
                const float p = exp2f(vals[nt][r] - m_i[r]);
                rs[r] += p;
                plds[wave][quad * 4 + r][nt * 16 + l16] = (__bf16)p;
            }
        #pragma unroll
        for (int r = 0; r < 4; ++r) {
            #pragma unroll
            for (int off = 1; off < 16; off <<= 1)
                rs[r] += __shfl_xor(rs[r], off);
            l_i[r] = l_i[r] * alpha[r] + rs[r];
        }
        #pragma unroll
        for (int nt = 0; nt < 4; ++nt)
            #pragma unroll
            for (int r = 0; r < 4; ++r) o_acc[nt][r] *= alpha[r];

        // O += P V  (P A-frags from own-wave LDS; V^T B-frags direct global)
        #pragma unroll
        for (int ks = 0; ks < 2; ++ks) {
            bf16x8 pf = *(const bf16x8*)&plds[wave][l16][ks * 32 + quad * 8];
            #pragma unroll
            for (int nt = 0; nt < 4; ++nt) {
                bf16x8 vf = *(const bf16x8*)(vtb + (size_t)(nt * 16 + l16) * TSEQ
                                             + s0 + ks * 32 + quad * 8);
                o_acc[nt] = __builtin_amdgcn_mfma_f32_16x16x32_bf16(pf, vf, o_acc[nt], 0, 0, 0);
            }
        }
    }

    // ---- merge the 4 waves' partial (m, l, O) ----
    float invl[4];
    #pragma unroll
    for (int r = 0; r < 4; ++r) invl[r] = (l_i[r] > 0.f) ? 1.0f / l_i[r] : 0.f;
    #pragma unroll
    for (int nt = 0; nt < 4; ++nt)
        #pragma unroll
        for (int r = 0; r < 4; ++r)
            plds[wave][quad * 4 + r][nt * 16 + l16] = (__bf16)(o_acc[nt][r] * invl[r]);
    if (l16 == 0) {
        #pragma unroll
        for (int r = 0; r < 4; ++r) {
            mlm[wave][quad * 4 + r] = m_i[r];
            mll[wave][quad * 4 + r] = l_i[r];
        }
    }
    __syncthreads();

    if (wave == 0) {
        float g[4][4], ginv[4];
        #pragma unroll
        for (int r = 0; r < 4; ++r) {
            const int rw = quad * 4 + r;
            const float ms = fmaxf(fmaxf(mlm[0][rw], mlm[1][rw]),
                                   fmaxf(mlm[2][rw], mlm[3][rw]));
            float gs = 0.f;
            #pragma unroll
            for (int w = 0; w < 4; ++w) {
                const float gg = exp2f(mlm[w][rw] - ms) * mll[w][rw];
                g[w][r] = gg;
                gs += gg;
            }
            ginv[r] = 1.0f / gs;
        }
        float oo[4][4];
        #pragma unroll
        for (int nt = 0; nt < 4; ++nt)
            #pragma unroll
            for (int r = 0; r < 4; ++r) {
                float o = 0.f;
                #pragma unroll
                for (int w = 0; w < 4; ++w)
                    o += g[w][r] * (float)plds[w][quad * 4 + r][nt * 16 + l16];
                oo[nt][r] = o * ginv[r];
            }
        #pragma unroll
        for (int nt = 0; nt < 4; ++nt)
            #pragma unroll
            for (int r = 0; r < 4; ++r)
                plds[0][quad * 4 + r][nt * 16 + l16] = (__bf16)oo[nt][r];

        // Projection: y = O @ Wproj + bproj  (B-frags from WprojT, contiguous)
        f32x4 res[4];
        #pragma unroll
        for (int nt = 0; nt < 4; ++nt) res[nt] = (f32x4){0.f, 0.f, 0.f, 0.f};
        #pragma unroll
        for (int ks = 0; ks < 2; ++ks) {
            bf16x8 of = *(const bf16x8*)&plds[0][l16][ks * 32 + quad * 8];
            #pragma unroll
            for (int nt = 0; nt < 4; ++nt) {
                bf16x8 wf = *(const bf16x8*)(wpt + (size_t)(nt * 16 + l16) * HS
                                             + ks * 32 + quad * 8);
                res[nt] = __builtin_amdgcn_mfma_f32_16x16x32_bf16(of, wf, res[nt], 0, 0, 0);
            }
        }
        #pragma unroll
        for (int nt = 0; nt < 4; ++nt) {
            const float bp = bproj[nt * 16 + l16];
            #pragma unroll
            for (int r = 0; r < 4; ++r)
                y[(tokbase + quad * 4 + r) * HS + nt * 16 + l16] = res[nt][r] + bp;
        }
    }
}

extern "C" void kernel_launch(void* const* d_in, const int* in_sizes, int n_in,
                              void* d_out, int out_size, void* d_ws, size_t ws_size,
                              hipStream_t stream) {
    const float* x     = (const float*)d_in[0];
    const float* v1    = (const float*)d_in[1];
    const float* wk    = (const float*)d_in[2];
    const float* wq    = (const float*)d_in[3];
    const float* wv    = (const float*)d_in[4];
    const float* wproj = (const float*)d_in[5];
    const float* bproj = (const float*)d_in[6];
    const float* lamb  = (const float*)d_in[7];

    float* out = (float*)d_out;
    // out1 region as bf16 scratch: k + vT (exactly fills 8.39MB)
    __bf16* kp  = (__bf16*)(out + OUTHALF);
    __bf16* vtp = kp + OUTHALF;
    // ws: q (4.19MB) | WT (288KB) | WprojT (8KB)
    __bf16* qp  = (__bf16*)d_ws;
    __bf16* wt  = qp + OUTHALF;
    __bf16* wpt = wt + (size_t)3 * HS * CEMB;

    prep_kernel<<<dim3(37), dim3(256), 0, stream>>>(wk, wq, wv, wproj, wt, wpt);

    qkv_kernel<<<dim3((int)(NTOK / 64)), dim3(256), 0, stream>>>(
        x, v1, wt, lamb, kp, qp, vtp);

    attn_kernel<<<dim3(BATCH * (TSEQ / 16)), dim3(256), 0, stream>>>(
        qp, kp, vtp, wpt, bproj, out);

    // Output 1: v1 passthrough (overwrites k/vT scratch).
    hipMemcpyAsync(out + OUTHALF, v1, OUTHALF * sizeof(float),
                   hipMemcpyDeviceToDevice, stream);
}

// Round 6
// 318.283 us; speedup vs baseline: 1.0368x; 1.0368x over previous
//
#include <hip/hip_runtime.h>
#include <hip/hip_bf16.h>

// Single-head causal attention with value-residual mix.
// B=16, T=2048, C=768, H=64. Inputs/outputs f32; internal compute bf16 MFMA.
// Outputs (concat flat, f32): y=[B,T,64], then v1=[B,T,64].

constexpr int BATCH = 16;
constexpr int TSEQ  = 2048;
constexpr int CEMB  = 768;
constexpr int HS    = 64;
constexpr size_t NTOK    = (size_t)BATCH * TSEQ;  // 32768
constexpr size_t OUTHALF = NTOK * HS;             // 2,097,152 elements

typedef __bf16 bf16x4 __attribute__((ext_vector_type(4)));
typedef __bf16 bf16x8 __attribute__((ext_vector_type(8)));
typedef float  f32x4  __attribute__((ext_vector_type(4)));

// ---------------------------------------------------------------------------
// Kernel 0: transpose weights to bf16.
// blocks 0..35: WT[m][h][c] = Wm[c][h];  block 36: WprojT[h'][h]
// ---------------------------------------------------------------------------
__global__ __launch_bounds__(256) void prep_kernel(
    const float* __restrict__ wk, const float* __restrict__ wq,
    const float* __restrict__ wv, const float* __restrict__ wproj,
    __bf16* __restrict__ wt, __bf16* __restrict__ wpt)
{
    __shared__ __bf16 t[64][66];
    const int bid = blockIdx.x;
    if (bid < 36) {
        const int m = bid / 12, c0 = (bid % 12) * 64;
        const float* src = (m == 0) ? wk : (m == 1) ? wq : wv;
        for (int i = threadIdx.x; i < 4096; i += 256) {
            const int c = i >> 6, h = i & 63;
            t[c][h] = (__bf16)src[(size_t)(c0 + c) * HS + h];
        }
        __syncthreads();
        for (int i = threadIdx.x; i < 4096; i += 256) {
            const int h = i >> 6, c = i & 63;
            wt[(size_t)m * HS * CEMB + (size_t)h * CEMB + c0 + c] = t[c][h];
        }
    } else {
        for (int i = threadIdx.x; i < 4096; i += 256) {
            const int h = i >> 6, hp = i & 63;
            t[h][hp] = (__bf16)wproj[i];
        }
        __syncthreads();
        for (int i = threadIdx.x; i < 4096; i += 256) {
            const int hp = i >> 6, h = i & 63;
            wpt[i] = t[h][hp];
        }
    }
}

// ---------------------------------------------------------------------------
// Kernel 1: QKV projection, no LDS, no barriers, x prefetched across c0.
// Grid: (B*T)/64 blocks x 256 threads (4 waves x 16 rows).
// ---------------------------------------------------------------------------
__global__ __launch_bounds__(256) void qkv_kernel(
    const float* __restrict__ x,      // [B*T, 768]
    const float* __restrict__ v1,     // [B*T, 64]
    const __bf16* __restrict__ wt,    // [3][64][768]
    const float* __restrict__ lamb_p,
    __bf16* __restrict__ kk,          // [B*T, 64]
    __bf16* __restrict__ qq,          // [B*T, 64]
    __bf16* __restrict__ vt)          // [B][64][2048]
{
    const int wave = threadIdx.x >> 6;
    const int lane = threadIdx.x & 63;
    const int l16  = lane & 15;
    const int quad = lane >> 4;
    const size_t row0 = (size_t)blockIdx.x * 64;

    f32x4 acc[3][4];
    #pragma unroll
    for (int m = 0; m < 3; ++m)
        #pragma unroll
        for (int nt = 0; nt < 4; ++nt)
            acc[m][nt] = (f32x4){0.f, 0.f, 0.f, 0.f};

    const size_t arow = row0 + wave * 16 + l16;
    const float* xrow = x + arow * CEMB + quad * 8;

    // x double-buffer: current c0 block in (a0,a1,b0,b1)
    f32x4 a0 = *(const f32x4*)(xrow);
    f32x4 a1 = *(const f32x4*)(xrow + 4);
    f32x4 b0 = *(const f32x4*)(xrow + 32);
    f32x4 b1 = *(const f32x4*)(xrow + 36);

    for (int c0 = 0; c0 < CEMB; c0 += 64) {
        const int cn = (c0 + 64 < CEMB) ? c0 + 64 : c0;   // clamp (reload last)
        f32x4 na0 = *(const f32x4*)(xrow + cn);
        f32x4 na1 = *(const f32x4*)(xrow + cn + 4);
        f32x4 nb0 = *(const f32x4*)(xrow + cn + 32);
        f32x4 nb1 = *(const f32x4*)(xrow + cn + 36);

        bf16x8 xa0, xa1;
        #pragma unroll
        for (int i = 0; i < 4; ++i) {
            xa0[i]     = (__bf16)a0[i];
            xa0[i + 4] = (__bf16)a1[i];
            xa1[i]     = (__bf16)b0[i];
            xa1[i + 4] = (__bf16)b1[i];
        }
        #pragma unroll
        for (int m = 0; m < 3; ++m) {
            const __bf16* wm = wt + (size_t)m * HS * CEMB;
            #pragma unroll
            for (int nt = 0; nt < 4; ++nt) {
                const __bf16* wr = wm + (size_t)(nt * 16 + l16) * CEMB + c0 + quad * 8;
                bf16x8 wf0 = *(const bf16x8*)(wr);
                bf16x8 wf1 = *(const bf16x8*)(wr + 32);
                acc[m][nt] = __builtin_amdgcn_mfma_f32_16x16x32_bf16(xa0, wf0, acc[m][nt], 0, 0, 0);
                acc[m][nt] = __builtin_amdgcn_mfma_f32_16x16x32_bf16(xa1, wf1, acc[m][nt], 0, 0, 0);
            }
        }
        a0 = na0; a1 = na1; b0 = nb0; b1 = nb1;
    }

    const float lam = lamb_p[0];
    const size_t rbase = row0 + wave * 16 + quad * 4;
    const int b  = (int)(rbase >> 11);
    const int t0 = (int)(rbase & 2047);
    __bf16* vtb = vt + (size_t)b * HS * TSEQ;
    #pragma unroll
    for (int nt = 0; nt < 4; ++nt) {
        const int col = nt * 16 + l16;
        bf16x4 pk;
        #pragma unroll
        for (int r = 0; r < 4; ++r) {
            const size_t idx = (rbase + r) * HS + col;
            kk[idx] = (__bf16)acc[0][nt][r];
            qq[idx] = (__bf16)acc[1][nt][r];
            pk[r] = (__bf16)((1.0f - lam) * acc[2][nt][r] + lam * v1[idx]);
        }
        *(bf16x4*)(vtb + (size_t)col * TSEQ + t0) = pk;
    }
}

// ---------------------------------------------------------------------------
// Kernel 2: flash attention + fused projection, work-balanced + prefetched.
// Grid: B*64 blocks; block handles q-tiles j=jp and 127-jp (uniform work).
// 4 waves split the s-tile range; K prefetched into reused registers; V loads
// hoisted ahead of softmax. Two-barrier merge + wave-0 projection per pass.
// ---------------------------------------------------------------------------
__global__ __launch_bounds__(256, 3) void attn_kernel(
    const __bf16* __restrict__ q,     // [B*T, 64]
    const __bf16* __restrict__ k,     // [B*T, 64]
    const __bf16* __restrict__ vt,    // [B][64][2048]
    const __bf16* __restrict__ wpt,   // [64][64] = Wproj^T
    const float* __restrict__ bproj,  // [64]
    float* __restrict__ y)            // [B*T, 64] f32
{
    __shared__ __bf16 plds[4][16][72];
    __shared__ float  mlm[4][16], mll[4][16];

    const int b    = blockIdx.x >> 6;
    const int jp   = blockIdx.x & 63;
    const int wave = threadIdx.x >> 6;
    const int lane = threadIdx.x & 63;
    const int l16  = lane & 15;
    const int quad = lane >> 4;

    const __bf16* kb  = k  + (size_t)b * TSEQ * HS;
    const __bf16* vtb = vt + (size_t)b * HS * TSEQ;
    const float sc2 = 0.125f * 1.44269504f;  // 1/sqrt(64) * log2(e)

    for (int pass = 0; pass < 2; ++pass) {
        const int j = pass ? (127 - jp) : jp;
        const size_t tokbase = (size_t)b * TSEQ + j * 16;
        const int tdiag = j >> 2;

        const __bf16* qbase = q + (tokbase + l16) * HS + quad * 8;
        bf16x8 qf0 = *(const bf16x8*)(qbase);
        bf16x8 qf1 = *(const bf16x8*)(qbase + 32);

        f32x4 o_acc[4];
        #pragma unroll
        for (int nt = 0; nt < 4; ++nt) o_acc[nt] = (f32x4){0.f, 0.f, 0.f, 0.f};
        float m_i[4], l_i[4];
        #pragma unroll
        for (int r = 0; r < 4; ++r) { m_i[r] = -1e30f; l_i[r] = 0.f; }

        // Preload K tile for this wave's first s-tile (clamped; harmless).
        bf16x8 kf[8];
        {
            const int s0c = (wave <= tdiag ? wave : tdiag) * 64;
            #pragma unroll
            for (int nt = 0; nt < 4; ++nt) {
                const __bf16* kbp = kb + (size_t)(s0c + nt * 16 + l16) * HS + quad * 8;
                kf[2 * nt]     = *(const bf16x8*)(kbp);
                kf[2 * nt + 1] = *(const bf16x8*)(kbp + 32);
            }
        }

        for (int t = wave; t <= tdiag; t += 4) {
            const int s0 = t * 64;
            // S = Q K^T with current kf
            f32x4 sc[4];
            #pragma unroll
            for (int nt = 0; nt < 4; ++nt) {
                f32x4 c = (f32x4){0.f, 0.f, 0.f, 0.f};
                c = __builtin_amdgcn_mfma_f32_16x16x32_bf16(qf0, kf[2 * nt], c, 0, 0, 0);
                c = __builtin_amdgcn_mfma_f32_16x16x32_bf16(qf1, kf[2 * nt + 1], c, 0, 0, 0);
                sc[nt] = c;
            }
            // Prefetch next K tile into kf (registers just freed by the MFMAs).
            {
                const int sn = ((t + 4 <= tdiag) ? (t + 4) : t) * 64;
                #pragma unroll
                for (int nt = 0; nt < 4; ++nt) {
                    const __bf16* kbp = kb + (size_t)(sn + nt * 16 + l16) * HS + quad * 8;
                    kf[2 * nt]     = *(const bf16x8*)(kbp);
                    kf[2 * nt + 1] = *(const bf16x8*)(kbp + 32);
                }
            }
            // Hoist V loads (consumed ~1.5k cycles later, after softmax).
            bf16x8 vf[8];
            #pragma unroll
            for (int ks = 0; ks < 2; ++ks)
                #pragma unroll
                for (int nt = 0; nt < 4; ++nt)
                    vf[ks * 4 + nt] = *(const bf16x8*)(vtb
                        + (size_t)(nt * 16 + l16) * TSEQ + s0 + ks * 32 + quad * 8);

            // Mask (diagonal tile) + scale, in place
            if (t == tdiag) {
                #pragma unroll
                for (int nt = 0; nt < 4; ++nt)
                    #pragma unroll
                    for (int r = 0; r < 4; ++r) {
                        const int s = s0 + nt * 16 + l16;
                        const int trow = j * 16 + quad * 4 + r;
                        sc[nt][r] = (s <= trow) ? sc[nt][r] * sc2 : -1e30f;
                    }
            } else {
                #pragma unroll
                for (int nt = 0; nt < 4; ++nt)
                    #pragma unroll
                    for (int r = 0; r < 4; ++r) sc[nt][r] *= sc2;
            }

            // Online softmax (exp2 domain)
            float mx[4];
            #pragma unroll
            for (int r = 0; r < 4; ++r) {
                mx[r] = fmaxf(fmaxf(sc[0][r], sc[1][r]), fmaxf(sc[2][r], sc[3][r]));
                #pragma unroll
                for (int off = 1; off < 16; off <<= 1)
                    mx[r] = fmaxf(mx[r], __shfl_xor(mx[r], off));
            }
            float alpha[4];
            #pragma unroll
            for (int r = 0; r < 4; ++r) {
                const float mn = fmaxf(m_i[r], mx[r]);
                alpha[r] = exp2f(m_i[r] - mn);
                m_i[r] = mn;
            }
            float rs[4] = {0.f, 0.f, 0.f, 0.f};
            #pragma unroll
            for (int nt = 0; nt < 4; ++nt)
                #pragma unroll
                for (int r = 0; r < 4; ++r) {
                    const float p = exp2f(sc[nt][r] - m_i[r]);
                    rs[r] += p;
                    plds[wave][quad * 4 + r][nt * 16 + l16] = (__bf16)p;
                }
            #pragma unroll
            for (int r = 0; r < 4; ++r) {
                #pragma unroll
                for (int off = 1; off < 16; off <<= 1)
                    rs[r] += __shfl_xor(rs[r], off);
                l_i[r] = l_i[r] * alpha[r] + rs[r];
            }
            #pragma unroll
            for (int nt = 0; nt < 4; ++nt)
                #pragma unroll
                for (int r = 0; r < 4; ++r) o_acc[nt][r] *= alpha[r];

            // O += P V
            #pragma unroll
            for (int ks = 0; ks < 2; ++ks) {
                bf16x8 pf = *(const bf16x8*)&plds[wave][l16][ks * 32 + quad * 8];
                #pragma unroll
                for (int nt = 0; nt < 4; ++nt)
                    o_acc[nt] = __builtin_amdgcn_mfma_f32_16x16x32_bf16(
                        pf, vf[ks * 4 + nt], o_acc[nt], 0, 0, 0);
            }
        }

        // ---- merge the 4 waves' partial (m, l, O) ----
        float invl[4];
        #pragma unroll
        for (int r = 0; r < 4; ++r) invl[r] = (l_i[r] > 0.f) ? 1.0f / l_i[r] : 0.f;
        #pragma unroll
        for (int nt = 0; nt < 4; ++nt)
            #pragma unroll
            for (int r = 0; r < 4; ++r)
                plds[wave][quad * 4 + r][nt * 16 + l16] = (__bf16)(o_acc[nt][r] * invl[r]);
        if (l16 == 0) {
            #pragma unroll
            for (int r = 0; r < 4; ++r) {
                mlm[wave][quad * 4 + r] = m_i[r];
                mll[wave][quad * 4 + r] = l_i[r];
            }
        }
        __syncthreads();

        if (wave == 0) {
            float g[4][4], ginv[4];
            #pragma unroll
            for (int r = 0; r < 4; ++r) {
                const int rw = quad * 4 + r;
                const float ms = fmaxf(fmaxf(mlm[0][rw], mlm[1][rw]),
                                       fmaxf(mlm[2][rw], mlm[3][rw]));
                float gs = 0.f;
                #pragma unroll
                for (int w = 0; w < 4; ++w) {
                    const float gg = exp2f(mlm[w][rw] - ms) * mll[w][rw];
                    g[w][r] = gg;
                    gs += gg;
                }
                ginv[r] = 1.0f / gs;
            }
            float oo[4][4];
            #pragma unroll
            for (int nt = 0; nt < 4; ++nt)
                #pragma unroll
                for (int r = 0; r < 4; ++r) {
                    float o = 0.f;
                    #pragma unroll
                    for (int w = 0; w < 4; ++w)
                        o += g[w][r] * (float)plds[w][quad * 4 + r][nt * 16 + l16];
                    oo[nt][r] = o * ginv[r];
                }
            #pragma unroll
            for (int nt = 0; nt < 4; ++nt)
                #pragma unroll
                for (int r = 0; r < 4; ++r)
                    plds[0][quad * 4 + r][nt * 16 + l16] = (__bf16)oo[nt][r];

            // y = O @ Wproj + bproj
            f32x4 res[4];
            #pragma unroll
            for (int nt = 0; nt < 4; ++nt) res[nt] = (f32x4){0.f, 0.f, 0.f, 0.f};
            #pragma unroll
            for (int ks = 0; ks < 2; ++ks) {
                bf16x8 of = *(const bf16x8*)&plds[0][l16][ks * 32 + quad * 8];
                #pragma unroll
                for (int nt = 0; nt < 4; ++nt) {
                    bf16x8 wf = *(const bf16x8*)(wpt + (size_t)(nt * 16 + l16) * HS
                                                 + ks * 32 + quad * 8);
                    res[nt] = __builtin_amdgcn_mfma_f32_16x16x32_bf16(of, wf, res[nt], 0, 0, 0);
                }
            }
            #pragma unroll
            for (int nt = 0; nt < 4; ++nt) {
                const float bp = bproj[nt * 16 + l16];
                #pragma unroll
                for (int r = 0; r < 4; ++r)
                    y[(tokbase + quad * 4 + r) * HS + nt * 16 + l16] = res[nt][r] + bp;
            }
        }
        __syncthreads();   // protect plds/mlm/mll before next pass
    }
}

extern "C" void kernel_launch(void* const* d_in, const int* in_sizes, int n_in,
                              void* d_out, int out_size, void* d_ws, size_t ws_size,
                              hipStream_t stream) {
    const float* x     = (const float*)d_in[0];
    const float* v1    = (const float*)d_in[1];
    const float* wk    = (const float*)d_in[2];
    const float* wq    = (const float*)d_in[3];
    const float* wv    = (const float*)d_in[4];
    const float* wproj = (const float*)d_in[5];
    const float* bproj = (const float*)d_in[6];
    const float* lamb  = (const float*)d_in[7];

    float* out = (float*)d_out;
    __bf16* kp  = (__bf16*)(out + OUTHALF);   // out1 region as bf16 scratch
    __bf16* vtp = kp + OUTHALF;
    __bf16* qp  = (__bf16*)d_ws;              // ws: q | WT | WprojT
    __bf16* wt  = qp + OUTHALF;
    __bf16* wpt = wt + (size_t)3 * HS * CEMB;

    prep_kernel<<<dim3(37), dim3(256), 0, stream>>>(wk, wq, wv, wproj, wt, wpt);

    qkv_kernel<<<dim3((int)(NTOK / 64)), dim3(256), 0, stream>>>(
        x, v1, wt, lamb, kp, qp, vtp);

    attn_kernel<<<dim3(BATCH * 64), dim3(256), 0, stream>>>(
        qp, kp, vtp, wpt, bproj, out);

    hipMemcpyAsync(out + OUTHALF, v1, OUTHALF * sizeof(float),
                   hipMemcpyDeviceToDevice, stream);
}

// Round 7
// 277.534 us; speedup vs baseline: 1.1890x; 1.1468x over previous
//
#include <hip/hip_runtime.h>
#include <hip/hip_bf16.h>

// Single-head causal attention with value-residual mix.
// B=16, T=2048, C=768, H=64. Inputs/outputs f32; internal compute bf16 MFMA.
// Outputs (concat flat, f32): y=[B,T,64], then v1=[B,T,64].

constexpr int BATCH = 16;
constexpr int TSEQ  = 2048;
constexpr int CEMB  = 768;
constexpr int HS    = 64;
constexpr size_t NTOK    = (size_t)BATCH * TSEQ;  // 32768
constexpr size_t OUTHALF = NTOK * HS;             // 2,097,152 elements

typedef __bf16 bf16x4 __attribute__((ext_vector_type(4)));
typedef __bf16 bf16x8 __attribute__((ext_vector_type(8)));
typedef float  f32x4  __attribute__((ext_vector_type(4)));

// ---------------------------------------------------------------------------
// Kernel 0: transpose weights to bf16.
// blocks 0..35: WT[m][h][c] = Wm[c][h];  block 36: WprojT[h'][h]
// ---------------------------------------------------------------------------
__global__ __launch_bounds__(256) void prep_kernel(
    const float* __restrict__ wk, const float* __restrict__ wq,
    const float* __restrict__ wv, const float* __restrict__ wproj,
    __bf16* __restrict__ wt, __bf16* __restrict__ wpt)
{
    __shared__ __bf16 t[64][66];
    const int bid = blockIdx.x;
    if (bid < 36) {
        const int m = bid / 12, c0 = (bid % 12) * 64;
        const float* src = (m == 0) ? wk : (m == 1) ? wq : wv;
        for (int i = threadIdx.x; i < 4096; i += 256) {
            const int c = i >> 6, h = i & 63;
            t[c][h] = (__bf16)src[(size_t)(c0 + c) * HS + h];
        }
        __syncthreads();
        for (int i = threadIdx.x; i < 4096; i += 256) {
            const int h = i >> 6, c = i & 63;
            wt[(size_t)m * HS * CEMB + (size_t)h * CEMB + c0 + c] = t[c][h];
        }
    } else {
        for (int i = threadIdx.x; i < 4096; i += 256) {
            const int h = i >> 6, hp = i & 63;
            t[h][hp] = (__bf16)wproj[i];
        }
        __syncthreads();
        for (int i = threadIdx.x; i < 4096; i += 256) {
            const int hp = i >> 6, h = i & 63;
            wpt[i] = t[h][hp];
        }
    }
}

// ---------------------------------------------------------------------------
// Kernel 1: QKV projection.
// Block = 256 thr / 4 waves, 64 tokens. Waves own DISJOINT output columns:
// wave w computes (m, nt=w) for m=k,q,v over all 64 tokens (4 A-tiles).
// x chunk staged f32->bf16 into double-buffered LDS (stride 88, 16B-aligned,
// 2-way banks); W frags (72 KB/wave total) register-prefetched from L2.
// One barrier per c0 iteration.
// ---------------------------------------------------------------------------
__global__ __launch_bounds__(256, 2) void qkv_kernel(
    const float* __restrict__ x,      // [B*T, 768]
    const float* __restrict__ v1,     // [B*T, 64]
    const __bf16* __restrict__ wt,    // [3][64][768]
    const float* __restrict__ lamb_p,
    __bf16* __restrict__ kk,          // [B*T, 64]
    __bf16* __restrict__ qq,          // [B*T, 64]
    __bf16* __restrict__ vt)          // [B][64][2048]
{
    __shared__ __bf16 xl[2][64][88];   // [buf][token][c], stride 88

    const int wave = threadIdx.x >> 6;
    const int lane = threadIdx.x & 63;
    const int l16  = lane & 15;
    const int quad = lane >> 4;
    const size_t row0 = (size_t)blockIdx.x * 64;

    // Staging role: thread covers token tok_s, columns [cq*16, cq*16+16)
    const int tok_s = threadIdx.x >> 2;
    const int cq    = threadIdx.x & 3;
    const float* xsrc = x + (row0 + tok_s) * CEMB + cq * 16;

    // This wave's W rows: col-tile nt=wave for each matrix m.
    const __bf16* wbase[3];
    #pragma unroll
    for (int m = 0; m < 3; ++m)
        wbase[m] = wt + ((size_t)m * HS + wave * 16 + l16) * CEMB + quad * 8;

    f32x4 acc[3][4];
    #pragma unroll
    for (int m = 0; m < 3; ++m)
        #pragma unroll
        for (int rt = 0; rt < 4; ++rt)
            acc[m][rt] = (f32x4){0.f, 0.f, 0.f, 0.f};

    // Prologue: stage chunk c0=0 into buf 0; load W frags for c0=0.
    {
        f32x4 t0 = *(const f32x4*)(xsrc);
        f32x4 t1 = *(const f32x4*)(xsrc + 4);
        f32x4 t2 = *(const f32x4*)(xsrc + 8);
        f32x4 t3 = *(const f32x4*)(xsrc + 12);
        bf16x8 lo, hi;
        #pragma unroll
        for (int i = 0; i < 4; ++i) {
            lo[i] = (__bf16)t0[i]; lo[i + 4] = (__bf16)t1[i];
            hi[i] = (__bf16)t2[i]; hi[i + 4] = (__bf16)t3[i];
        }
        *(bf16x8*)&xl[0][tok_s][cq * 16]     = lo;
        *(bf16x8*)&xl[0][tok_s][cq * 16 + 8] = hi;
    }
    bf16x8 wc[3][2];
    #pragma unroll
    for (int m = 0; m < 3; ++m)
        #pragma unroll
        for (int ks = 0; ks < 2; ++ks)
            wc[m][ks] = *(const bf16x8*)(wbase[m] + ks * 32);
    __syncthreads();

    for (int c0 = 0; c0 < CEMB; c0 += 64) {
        const int buf = (c0 >> 6) & 1;
        const bool notlast = (c0 + 64 < CEMB);

        // Issue next x chunk loads + next W loads early (latency overlap).
        f32x4 nx0, nx1, nx2, nx3;
        bf16x8 wn[3][2];
        if (notlast) {
            const float* xs = xsrc + c0 + 64;
            nx0 = *(const f32x4*)(xs);
            nx1 = *(const f32x4*)(xs + 4);
            nx2 = *(const f32x4*)(xs + 8);
            nx3 = *(const f32x4*)(xs + 12);
            #pragma unroll
            for (int m = 0; m < 3; ++m)
                #pragma unroll
                for (int ks = 0; ks < 2; ++ks)
                    wn[m][ks] = *(const bf16x8*)(wbase[m] + c0 + 64 + ks * 32);
        }

        // Compute on current buffer.
        #pragma unroll
        for (int ks = 0; ks < 2; ++ks) {
            bf16x8 a[4];
            #pragma unroll
            for (int rt = 0; rt < 4; ++rt)
                a[rt] = *(const bf16x8*)&xl[buf][rt * 16 + l16][ks * 32 + quad * 8];
            #pragma unroll
            for (int m = 0; m < 3; ++m)
                #pragma unroll
                for (int rt = 0; rt < 4; ++rt)
                    acc[m][rt] = __builtin_amdgcn_mfma_f32_16x16x32_bf16(
                        a[rt], wc[m][ks], acc[m][rt], 0, 0, 0);
        }

        if (notlast) {
            bf16x8 lo, hi;
            #pragma unroll
            for (int i = 0; i < 4; ++i) {
                lo[i] = (__bf16)nx0[i]; lo[i + 4] = (__bf16)nx1[i];
                hi[i] = (__bf16)nx2[i]; hi[i + 4] = (__bf16)nx3[i];
            }
            *(bf16x8*)&xl[buf ^ 1][tok_s][cq * 16]     = lo;
            *(bf16x8*)&xl[buf ^ 1][tok_s][cq * 16 + 8] = hi;
            #pragma unroll
            for (int m = 0; m < 3; ++m)
                #pragma unroll
                for (int ks = 0; ks < 2; ++ks)
                    wc[m][ks] = wn[m][ks];
            __syncthreads();
        }
    }

    // Epilogue. D layout per tile: token = rt*16 + quad*4 + r, col = wave*16+l16.
    const float lam = lamb_p[0];
    const int col = wave * 16 + l16;
    const int b  = (int)(row0 >> 11);
    __bf16* vtb = vt + (size_t)b * HS * TSEQ + (size_t)col * TSEQ;
    #pragma unroll
    for (int rt = 0; rt < 4; ++rt) {
        const size_t tok0 = row0 + rt * 16 + quad * 4;
        bf16x4 pk;
        #pragma unroll
        for (int r = 0; r < 4; ++r) {
            const size_t idx = (tok0 + r) * HS + col;
            kk[idx] = (__bf16)acc[0][rt][r];
            qq[idx] = (__bf16)acc[1][rt][r];
            pk[r] = (__bf16)((1.0f - lam) * acc[2][rt][r] + lam * v1[idx]);
        }
        *(bf16x4*)(vtb + (tok0 & 2047)) = pk;
    }
}

// ---------------------------------------------------------------------------
// Kernel 2: flash attention + fused projection (unchanged from round 6).
// ---------------------------------------------------------------------------
__global__ __launch_bounds__(256, 3) void attn_kernel(
    const __bf16* __restrict__ q,     // [B*T, 64]
    const __bf16* __restrict__ k,     // [B*T, 64]
    const __bf16* __restrict__ vt,    // [B][64][2048]
    const __bf16* __restrict__ wpt,   // [64][64] = Wproj^T
    const float* __restrict__ bproj,  // [64]
    float* __restrict__ y)            // [B*T, 64] f32
{
    __shared__ __bf16 plds[4][16][72];
    __shared__ float  mlm[4][16], mll[4][16];

    const int b    = blockIdx.x >> 6;
    const int jp   = blockIdx.x & 63;
    const int wave = threadIdx.x >> 6;
    const int lane = threadIdx.x & 63;
    const int l16  = lane & 15;
    const int quad = lane >> 4;

    const __bf16* kb  = k  + (size_t)b * TSEQ * HS;
    const __bf16* vtb = vt + (size_t)b * HS * TSEQ;
    const float sc2 = 0.125f * 1.44269504f;  // 1/sqrt(64) * log2(e)

    for (int pass = 0; pass < 2; ++pass) {
        const int j = pass ? (127 - jp) : jp;
        const size_t tokbase = (size_t)b * TSEQ + j * 16;
        const int tdiag = j >> 2;

        const __bf16* qbase = q + (tokbase + l16) * HS + quad * 8;
        bf16x8 qf0 = *(const bf16x8*)(qbase);
        bf16x8 qf1 = *(const bf16x8*)(qbase + 32);

        f32x4 o_acc[4];
        #pragma unroll
        for (int nt = 0; nt < 4; ++nt) o_acc[nt] = (f32x4){0.f, 0.f, 0.f, 0.f};
        float m_i[4], l_i[4];
        #pragma unroll
        for (int r = 0; r < 4; ++r) { m_i[r] = -1e30f; l_i[r] = 0.f; }

        bf16x8 kf[8];
        {
            const int s0c = (wave <= tdiag ? wave : tdiag) * 64;
            #pragma unroll
            for (int nt = 0; nt < 4; ++nt) {
                const __bf16* kbp = kb + (size_t)(s0c + nt * 16 + l16) * HS + quad * 8;
                kf[2 * nt]     = *(const bf16x8*)(kbp);
                kf[2 * nt + 1] = *(const bf16x8*)(kbp + 32);
            }
        }

        for (int t = wave; t <= tdiag; t += 4) {
            const int s0 = t * 64;
            f32x4 sc[4];
            #pragma unroll
            for (int nt = 0; nt < 4; ++nt) {
                f32x4 c = (f32x4){0.f, 0.f, 0.f, 0.f};
                c = __builtin_amdgcn_mfma_f32_16x16x32_bf16(qf0, kf[2 * nt], c, 0, 0, 0);
                c = __builtin_amdgcn_mfma_f32_16x16x32_bf16(qf1, kf[2 * nt + 1], c, 0, 0, 0);
                sc[nt] = c;
            }
            {
                const int sn = ((t + 4 <= tdiag) ? (t + 4) : t) * 64;
                #pragma unroll
                for (int nt = 0; nt < 4; ++nt) {
                    const __bf16* kbp = kb + (size_t)(sn + nt * 16 + l16) * HS + quad * 8;
                    kf[2 * nt]     = *(const bf16x8*)(kbp);
                    kf[2 * nt + 1] = *(const bf16x8*)(kbp + 32);
                }
            }
            bf16x8 vf[8];
            #pragma unroll
            for (int ks = 0; ks < 2; ++ks)
                #pragma unroll
                for (int nt = 0; nt < 4; ++nt)
                    vf[ks * 4 + nt] = *(const bf16x8*)(vtb
                        + (size_t)(nt * 16 + l16) * TSEQ + s0 + ks * 32 + quad * 8);

            if (t == tdiag) {
                #pragma unroll
                for (int nt = 0; nt < 4; ++nt)
                    #pragma unroll
                    for (int r = 0; r < 4; ++r) {
                        const int s = s0 + nt * 16 + l16;
                        const int trow = j * 16 + quad * 4 + r;
                        sc[nt][r] = (s <= trow) ? sc[nt][r] * sc2 : -1e30f;
                    }
            } else {
                #pragma unroll
                for (int nt = 0; nt < 4; ++nt)
                    #pragma unroll
                    for (int r = 0; r < 4; ++r) sc[nt][r] *= sc2;
            }

            float mx[4];
            #pragma unroll
            for (int r = 0; r < 4; ++r) {
                mx[r] = fmaxf(fmaxf(sc[0][r], sc[1][r]), fmaxf(sc[2][r], sc[3][r]));
                #pragma unroll
                for (int off = 1; off < 16; off <<= 1)
                    mx[r] = fmaxf(mx[r], __shfl_xor(mx[r], off));
            }
            float alpha[4];
            #pragma unroll
            for (int r = 0; r < 4; ++r) {
                const float mn = fmaxf(m_i[r], mx[r]);
                alpha[r] = exp2f(m_i[r] - mn);
                m_i[r] = mn;
            }
            float rs[4] = {0.f, 0.f, 0.f, 0.f};
            #pragma unroll
            for (int nt = 0; nt < 4; ++nt)
                #pragma unroll
                for (int r = 0; r < 4; ++r) {
                    const float p = exp2f(sc[nt][r] - m_i[r]);
                    rs[r] += p;
                    plds[wave][quad * 4 + r][nt * 16 + l16] = (__bf16)p;
                }
            #pragma unroll
            for (int r = 0; r < 4; ++r) {
                #pragma unroll
                for (int off = 1; off < 16; off <<= 1)
                    rs[r] += __shfl_xor(rs[r], off);
                l_i[r] = l_i[r] * alpha[r] + rs[r];
            }
            #pragma unroll
            for (int nt = 0; nt < 4; ++nt)
                #pragma unroll
                for (int r = 0; r < 4; ++r) o_acc[nt][r] *= alpha[r];

            #pragma unroll
            for (int ks = 0; ks < 2; ++ks) {
                bf16x8 pf = *(const bf16x8*)&plds[wave][l16][ks * 32 + quad * 8];
                #pragma unroll
                for (int nt = 0; nt < 4; ++nt)
                    o_acc[nt] = __builtin_amdgcn_mfma_f32_16x16x32_bf16(
                        pf, vf[ks * 4 + nt], o_acc[nt], 0, 0, 0);
            }
        }

        float invl[4];
        #pragma unroll
        for (int r = 0; r < 4; ++r) invl[r] = (l_i[r] > 0.f) ? 1.0f / l_i[r] : 0.f;
        #pragma unroll
        for (int nt = 0; nt < 4; ++nt)
            #pragma unroll
            for (int r = 0; r < 4; ++r)
                plds[wave][quad * 4 + r][nt * 16 + l16] = (__bf16)(o_acc[nt][r] * invl[r]);
        if (l16 == 0) {
            #pragma unroll
            for (int r = 0; r < 4; ++r) {
                mlm[wave][quad * 4 + r] = m_i[r];
                mll[wave][quad * 4 + r] = l_i[r];
            }
        }
        __syncthreads();

        if (wave == 0) {
            float g[4][4], ginv[4];
            #pragma unroll
            for (int r = 0; r < 4; ++r) {
                const int rw = quad * 4 + r;
                const float ms = fmaxf(fmaxf(mlm[0][rw], mlm[1][rw]),
                                       fmaxf(mlm[2][rw], mlm[3][rw]));
                float gs = 0.f;
                #pragma unroll
                for (int w = 0; w < 4; ++w) {
                    const float gg = exp2f(mlm[w][rw] - ms) * mll[w][rw];
                    g[w][r] = gg;
                    gs += gg;
                }
                ginv[r] = 1.0f / gs;
            }
            float oo[4][4];
            #pragma unroll
            for (int nt = 0; nt < 4; ++nt)
                #pragma unroll
                for (int r = 0; r < 4; ++r) {
                    float o = 0.f;
                    #pragma unroll
                    for (int w = 0; w < 4; ++w)
                        o += g[w][r] * (float)plds[w][quad * 4 + r][nt * 16 + l16];
                    oo[nt][r] = o * ginv[r];
                }
            #pragma unroll
            for (int nt = 0; nt < 4; ++nt)
                #pragma unroll
                for (int r = 0; r < 4; ++r)
                    plds[0][quad * 4 + r][nt * 16 + l16] = (__bf16)oo[nt][r];

            f32x4 res[4];
            #pragma unroll
            for (int nt = 0; nt < 4; ++nt) res[nt] = (f32x4){0.f, 0.f, 0.f, 0.f};
            #pragma unroll
            for (int ks = 0; ks < 2; ++ks) {
                bf16x8 of = *(const bf16x8*)&plds[0][l16][ks * 32 + quad * 8];
                #pragma unroll
                for (int nt = 0; nt < 4; ++nt) {
                    bf16x8 wf = *(const bf16x8*)(wpt + (size_t)(nt * 16 + l16) * HS
                                                 + ks * 32 + quad * 8);
                    res[nt] = __builtin_amdgcn_mfma_f32_16x16x32_bf16(of, wf, res[nt], 0, 0, 0);
                }
            }
            #pragma unroll
            for (int nt = 0; nt < 4; ++nt) {
                const float bp = bproj[nt * 16 + l16];
                #pragma unroll
                for (int r = 0; r < 4; ++r)
                    y[(tokbase + quad * 4 + r) * HS + nt * 16 + l16] = res[nt][r] + bp;
            }
        }
        __syncthreads();
    }
}

// ---------------------------------------------------------------------------
// Kernel 3: v1 passthrough f32->f32 (replaces SDMA memcpy).
// ---------------------------------------------------------------------------
__global__ __launch_bounds__(256) void copy_kernel(
    const float* __restrict__ src, float* __restrict__ dst)
{
    const size_t i = ((size_t)blockIdx.x * 256 + threadIdx.x) * 4;
    *(f32x4*)(dst + i) = *(const f32x4*)(src + i);
}

extern "C" void kernel_launch(void* const* d_in, const int* in_sizes, int n_in,
                              void* d_out, int out_size, void* d_ws, size_t ws_size,
                              hipStream_t stream) {
    const float* x     = (const float*)d_in[0];
    const float* v1    = (const float*)d_in[1];
    const float* wk    = (const float*)d_in[2];
    const float* wq    = (const float*)d_in[3];
    const float* wv    = (const float*)d_in[4];
    const float* wproj = (const float*)d_in[5];
    const float* bproj = (const float*)d_in[6];
    const float* lamb  = (const float*)d_in[7];

    float* out = (float*)d_out;
    __bf16* kp  = (__bf16*)(out + OUTHALF);   // out1 region as bf16 scratch
    __bf16* vtp = kp + OUTHALF;
    __bf16* qp  = (__bf16*)d_ws;              // ws: q | WT | WprojT
    __bf16* wt  = qp + OUTHALF;
    __bf16* wpt = wt + (size_t)3 * HS * CEMB;

    prep_kernel<<<dim3(37), dim3(256), 0, stream>>>(wk, wq, wv, wproj, wt, wpt);

    qkv_kernel<<<dim3((int)(NTOK / 64)), dim3(256), 0, stream>>>(
        x, v1, wt, lamb, kp, qp, vtp);

    attn_kernel<<<dim3(BATCH * 64), dim3(256), 0, stream>>>(
        qp, kp, vtp, wpt, bproj, out);

    copy_kernel<<<dim3((int)(OUTHALF / (256 * 4))), dim3(256), 0, stream>>>(
        v1, out + OUTHALF);
}